// Round 7
// baseline (11.486 us; speedup 1.0000x reference)
//
#include <hip/hip_runtime.h>
#include <hip/hip_bf16.h>

// FWHT for 12 qubits (N=4096), batch 256, real/imag planes.
// out = FWHT(x) / 64  (H = (H2)^{⊗12}, entries ±1/64; H is never read).
//
// Fused real+imag single pass: 3 radix-16 rounds (bits [3:0], [7:4],
// [11:8]), 2 barriers total. Both planes' loads issue at kernel entry.
// LDS: TWO separate pad-17 float arrays (the b32 pattern proven
// conflict-free in rounds 2/4) — the float2 version aliased 4-way
// because base stride 34 dwords ≡ 2 (mod 32) banks.

#define NN 4096
#define T  256
#define PAD (NN + NN / 16)                  // 4352 floats

__device__ __forceinline__ void fwht16(float x[16]) {
#pragma unroll
    for (int s = 0; s < 4; ++s) {
        const int st = 1 << s;
#pragma unroll
        for (int i = 0; i < 16; ++i) {
            if ((i & st) == 0) {
                const float a = x[i];
                const float b = x[i + st];
                x[i]      = a + b;
                x[i + st] = a - b;
            }
        }
    }
}

__global__ __launch_bounds__(T)
void fwht_kernel(const float* __restrict__ gr,
                 const float* __restrict__ gi,
                 float* __restrict__ out) {
    __shared__ float sr[PAD];               // 17 KiB
    __shared__ float si[PAD];               // 17 KiB

    const int b = blockIdx.x;               // batch 0..255
    const int t = threadIdx.x;              // 0..255

    const float4* pr = (const float4*)(gr + (size_t)b * NN + t * 16);
    const float4* pi = (const float4*)(gi + (size_t)b * NN + t * 16);
    float*        dr = out + (size_t)b * NN;
    float*        di = out + (size_t)(256 + b) * NN;

    // ---- load both planes up front (8x dwordx4/thread) ----
    float xr[16], xi[16];
#pragma unroll
    for (int k = 0; k < 4; ++k) {
        const float4 r = pr[k];
        xr[4 * k + 0] = r.x; xr[4 * k + 1] = r.y;
        xr[4 * k + 2] = r.z; xr[4 * k + 3] = r.w;
    }
#pragma unroll
    for (int k = 0; k < 4; ++k) {
        const float4 i = pi[k];
        xi[4 * k + 0] = i.x; xi[4 * k + 1] = i.y;
        xi[4 * k + 2] = i.z; xi[4 * k + 3] = i.w;
    }

    // ---- Round A: bits [3:0] (thread t owns n = t*16 + r) ----
    fwht16(xr);
    fwht16(xi);
#pragma unroll
    for (int r = 0; r < 16; ++r) sr[t * 17 + r] = xr[r];
#pragma unroll
    for (int r = 0; r < 16; ++r) si[t * 17 + r] = xi[r];
    __syncthreads();

    // ---- Round B: bits [7:4]; thread = (P = t>>4, R = t&15) ----
    const int baseB = (t >> 4) * 272 + (t & 15);
#pragma unroll
    for (int q = 0; q < 16; ++q) xr[q] = sr[baseB + q * 17];
#pragma unroll
    for (int q = 0; q < 16; ++q) xi[q] = si[baseB + q * 17];
    fwht16(xr);
    fwht16(xi);
#pragma unroll
    for (int q = 0; q < 16; ++q) sr[baseB + q * 17] = xr[q];  // same addrs
#pragma unroll
    for (int q = 0; q < 16; ++q) si[baseB + q * 17] = xi[q];
    __syncthreads();

    // ---- Round C: bits [11:8]; thread = (Q = t>>4, R = t&15) ----
    const int baseC = (t >> 4) * 17 + (t & 15);
#pragma unroll
    for (int p = 0; p < 16; ++p) xr[p] = sr[baseC + p * 272];
#pragma unroll
    for (int p = 0; p < 16; ++p) xi[p] = si[baseC + p * 272];
    fwht16(xr);
    fwht16(xi);

    // ---- scale 1/64, store both planes (1 KiB contiguous / instr) ----
    const float sc = 0.015625f;             // (1/sqrt(2))^12
#pragma unroll
    for (int p = 0; p < 16; ++p) dr[p * 256 + t] = xr[p] * sc;
#pragma unroll
    for (int p = 0; p < 16; ++p) di[p * 256 + t] = xi[p] * sc;
}

extern "C" void kernel_launch(void* const* d_in, const int* in_sizes, int n_in,
                              void* d_out, int out_size, void* d_ws, size_t ws_size,
                              hipStream_t stream) {
    const float* gr = (const float*)d_in[0];
    const float* gi = (const float*)d_in[1];
    float* out = (float*)d_out;

    fwht_kernel<<<256, T, 0, stream>>>(gr, gi, out);
}

// Round 8
// 10.182 us; speedup vs baseline: 1.1281x; 1.1281x over previous
//
#include <hip/hip_runtime.h>
#include <hip/hip_bf16.h>

// FWHT for 12 qubits (N=4096), batch 256, real/imag planes.
// out = FWHT(x) / 64  (H = (H2)^{⊗12}, entries ±1/64; H is never read).
//
// Structure: R4's sequential two-vector pipeline (best measured), now
// SKEWED through two separate pad-17 LDS arrays:
//   P1: A_r          P2: B_r || A_i      P3: C_r+store_r || B_i
//   P4: C_i+store_i
// 3 barriers (vs 5), stores split across P3/P4, each middle phase mixes
// an LDS-bound stream with a VALU-bound stream. Radix-16 rounds over
// bits [3:0], [7:4], [11:8]; pad n -> (n>>4)*17 + (n&15) (proven
// conflict-free b32 pattern). Grid 256 = 1 block/CU, 4 waves.

#define NN 4096
#define T  256
#define PAD (NN + NN / 16)                  // 4352 floats = 17 KiB

__device__ __forceinline__ void fwht16(float x[16]) {
#pragma unroll
    for (int s = 0; s < 4; ++s) {
        const int st = 1 << s;
#pragma unroll
        for (int i = 0; i < 16; ++i) {
            if ((i & st) == 0) {
                const float a = x[i];
                const float b = x[i + st];
                x[i]      = a + b;
                x[i + st] = a - b;
            }
        }
    }
}

__global__ __launch_bounds__(T)
void fwht_kernel(const float* __restrict__ gr,
                 const float* __restrict__ gi,
                 float* __restrict__ out) {
    __shared__ float sr[PAD];
    __shared__ float si[PAD];

    const int b = blockIdx.x;               // batch 0..255
    const int t = threadIdx.x;              // 0..255

    const float4* pr = (const float4*)(gr + (size_t)b * NN + t * 16);
    const float4* pi = (const float4*)(gi + (size_t)b * NN + t * 16);
    float*        dr = out + (size_t)b * NN;
    float*        di = out + (size_t)(256 + b) * NN;

    // ---- all loads issue at entry (8x dwordx4/thread) ----
    float xr[16], xi[16];
#pragma unroll
    for (int k = 0; k < 4; ++k) {
        const float4 r = pr[k];
        xr[4 * k + 0] = r.x; xr[4 * k + 1] = r.y;
        xr[4 * k + 2] = r.z; xr[4 * k + 3] = r.w;
    }
#pragma unroll
    for (int k = 0; k < 4; ++k) {
        const float4 i = pi[k];
        xi[4 * k + 0] = i.x; xi[4 * k + 1] = i.y;
        xi[4 * k + 2] = i.z; xi[4 * k + 3] = i.w;
    }

    const int baseB = (t >> 4) * 272 + (t & 15);   // bits [7:4] gather
    const int baseC = (t >> 4) * 17 + (t & 15);    // bits [11:8] gather
    const float sc = 0.015625f;                    // (1/sqrt(2))^12

    // ---- P1: A_r ----
    fwht16(xr);
#pragma unroll
    for (int r = 0; r < 16; ++r) sr[t * 17 + r] = xr[r];
    __syncthreads();                                // bar1

    // ---- P2: B_r || A_i ----
#pragma unroll
    for (int q = 0; q < 16; ++q) xr[q] = sr[baseB + q * 17];
    fwht16(xr);
#pragma unroll
    for (int q = 0; q < 16; ++q) sr[baseB + q * 17] = xr[q];  // same addrs

    fwht16(xi);
#pragma unroll
    for (int r = 0; r < 16; ++r) si[t * 17 + r] = xi[r];
    __syncthreads();                                // bar2

    // ---- P3: C_r + store_r || B_i ----
#pragma unroll
    for (int p = 0; p < 16; ++p) xr[p] = sr[baseC + p * 272];
    fwht16(xr);
#pragma unroll
    for (int p = 0; p < 16; ++p) dr[p * 256 + t] = xr[p] * sc;

#pragma unroll
    for (int q = 0; q < 16; ++q) xi[q] = si[baseB + q * 17];
    fwht16(xi);
#pragma unroll
    for (int q = 0; q < 16; ++q) si[baseB + q * 17] = xi[q];
    __syncthreads();                                // bar3

    // ---- P4: C_i + store_i ----
#pragma unroll
    for (int p = 0; p < 16; ++p) xi[p] = si[baseC + p * 272];
    fwht16(xi);
#pragma unroll
    for (int p = 0; p < 16; ++p) di[p * 256 + t] = xi[p] * sc;
}

extern "C" void kernel_launch(void* const* d_in, const int* in_sizes, int n_in,
                              void* d_out, int out_size, void* d_ws, size_t ws_size,
                              hipStream_t stream) {
    const float* gr = (const float*)d_in[0];
    const float* gi = (const float*)d_in[1];
    float* out = (float*)d_out;

    fwht_kernel<<<256, T, 0, stream>>>(gr, gi, out);
}